// Round 1
// baseline (715.368 us; speedup 1.0000x reference)
//
#include <hip/hip_runtime.h>

// Problem constants (from reference):
// x:       (128, 3, 4, 32, 32) fp32        strides n:12288 c:4096 i:1024 xx:32 yy:1
// tensors: (3, 8, 31, 31, 4,4,4,4, 6) fp32 -> W[c,p,site, m=ijkl, o], 1536 floats per (c,p,site)
// bias:    (8, 31, 31, 6) fp32
// out:     (128, 8, 6, 31, 31) fp32        site is fastest dim
//
// One block per site. 384 threads.
//   Stage: AB[c][n][16] = a_i*b_j, CD[c][n][16] = c_k*d_l   (48 KB LDS)
//   K-loop: 12 chunks of 64 m-values of W staged to LDS (12 KB)
//   MAC: thread tile 4n x 4po; A-values built on the fly as AB*CD (broadcast LDS reads)
// Block swizzle: site = (bid%8)*120 + bid/8 so consecutive sites share an XCD L2,
// letting the scattered 4B output stores merge into full 64B lines in L2.

__global__ __launch_bounds__(384, 3)
void ttn_conv_fp32(const float* __restrict__ x,
                   const float* __restrict__ tensors,
                   const float* __restrict__ bias,
                   float* __restrict__ out) {
  __shared__ float sAB[3 * 128 * 16];
  __shared__ float sCD[3 * 128 * 16];
  __shared__ float sW[64 * 48];

  const int bid = blockIdx.x;
  const int site = (bid < 960) ? ((bid & 7) * 120 + (bid >> 3)) : 960;
  const int xx = site / 31;
  const int yy = site - xx * 31;
  const int t = threadIdx.x;

  // ---- stage AB / CD: one (n,c) pair per thread (384 = 128*3) ----
  {
    const int c = t % 3, n = t / 3;              // n*3 + c == t
    const float* xp = x + (size_t)t * 4096 + xx * 32 + yy;
    float av[4], bv[4], cv[4], dv[4];
#pragma unroll
    for (int i = 0; i < 4; ++i) {
      const float* r0 = xp + i * 1024;
      av[i] = r0[0];        // x[n,c,i,xx,  yy  ]
      cv[i] = r0[1];        // x[n,c,i,xx,  yy+1]
      bv[i] = r0[32];       // x[n,c,i,xx+1,yy  ]
      dv[i] = r0[33];       // x[n,c,i,xx+1,yy+1]
    }
    float* ab = &sAB[(c * 128 + n) * 16];
    float* cd = &sCD[(c * 128 + n) * 16];
#pragma unroll
    for (int i = 0; i < 4; ++i)
#pragma unroll
      for (int j = 0; j < 4; ++j) {
        ab[i * 4 + j] = av[i] * bv[j];
        cd[i * 4 + j] = cv[i] * dv[j];
      }
  }

  const int pog = t % 12;   // po tile: po = pog*4 + q, q in 0..3 (48 po total)
  const int ng  = t / 12;   // n  tile: n  = ng*4 + r,  r in 0..3 (128 n total)

  float acc[4][4] = {};

  for (int c = 0; c < 3; ++c) {
    for (int mb = 0; mb < 4; ++mb) {     // 4 chunks of 64 m per c  -> 12 chunks total
      __syncthreads();
      // ---- stage sW[64][48] for m in [mb*64, mb*64+64) ----
      {
        const int pgrp = t / 96, tf = t % 96;   // 96 float4 = 384 floats per p-chunk
#pragma unroll
        for (int pp = 0; pp < 2; ++pp) {
          const int p = pp * 4 + pgrp;
          const float* src = tensors +
              ((size_t)((c * 8 + p) * 961 + site) * 256 + mb * 64) * 6 + tf * 4;
          const float4 v = *(const float4*)src;
          const float vv[4] = {v.x, v.y, v.z, v.w};
          const int f = tf * 4;
#pragma unroll
          for (int u = 0; u < 4; ++u) {
            const int f2 = f + u;                // = m_local*6 + o
            sW[(f2 / 6) * 48 + p * 6 + (f2 % 6)] = vv[u];
          }
        }
      }
      __syncthreads();

      // ---- MAC: 64 m-values = 4 ij x 16 kl ----
#pragma unroll
      for (int klq = 0; klq < 4; ++klq) {
        float4 cd4[4];
#pragma unroll
        for (int r = 0; r < 4; ++r)
          cd4[r] = *(const float4*)&sCD[(c * 128 + ng * 4 + r) * 16 + klq * 4];
#pragma unroll
        for (int ij4 = 0; ij4 < 4; ++ij4) {
          float abv[4];
#pragma unroll
          for (int r = 0; r < 4; ++r)
            abv[r] = sAB[(c * 128 + ng * 4 + r) * 16 + mb * 4 + ij4];
          float4 w4[4];
#pragma unroll
          for (int s = 0; s < 4; ++s)
            w4[s] = *(const float4*)&sW[(ij4 * 16 + klq * 4 + s) * 48 + pog * 4];
#pragma unroll
          for (int r = 0; r < 4; ++r) {
            const float cdr[4] = {cd4[r].x, cd4[r].y, cd4[r].z, cd4[r].w};
#pragma unroll
            for (int s = 0; s < 4; ++s) {
              const float A = abv[r] * cdr[s];
              acc[r][0] = fmaf(A, w4[s].x, acc[r][0]);
              acc[r][1] = fmaf(A, w4[s].y, acc[r][1]);
              acc[r][2] = fmaf(A, w4[s].z, acc[r][2]);
              acc[r][3] = fmaf(A, w4[s].w, acc[r][3]);
            }
          }
        }
      }
    }
  }

  // ---- epilogue: bias + scattered stores (merged in L2 via site swizzle) ----
#pragma unroll
  for (int q = 0; q < 4; ++q) {
    const int po = pog * 4 + q;
    const int p = po / 6, o = po % 6;
    const float bq = bias[(p * 961 + site) * 6 + o];
#pragma unroll
    for (int r = 0; r < 4; ++r) {
      const int n = ng * 4 + r;
      out[(size_t)((n * 8 + p) * 6 + o) * 961 + site] = acc[r][q] + bq;
    }
  }
}

extern "C" void kernel_launch(void* const* d_in, const int* in_sizes, int n_in,
                              void* d_out, int out_size, void* d_ws, size_t ws_size,
                              hipStream_t stream) {
  const float* x       = (const float*)d_in[0];
  const float* tensors = (const float*)d_in[1];
  const float* bias    = (const float*)d_in[2];
  float* out           = (float*)d_out;
  hipLaunchKernelGGL(ttn_conv_fp32, dim3(961), dim3(384), 0, stream,
                     x, tensors, bias, out);
}